// Round 2
// baseline (5120.338 us; speedup 1.0000x reference)
//
#include <hip/hip_runtime.h>
#include <hip/hip_bf16.h>

// Problem constants (match reference)
#define MM 12288
#define NCH 8      // B * C_IN
#define COUT 16
#define KK 5

#define ROWS 4                 // rows per wave
#define WAVES 12               // waves per block
#define BLOCK (WAVES * 64)     // 768 threads
#define RPB (ROWS * WAVES)     // 48 rows per block -> grid = 256 = 1 block/CU
#define CHUNK 1536             // columns per LDS chunk
#define NCHUNK (MM / CHUNK)    // 8
#define F4PC (NCH * CHUNK / 4) // float4 per chunk = 3072
#define F4PT (F4PC / BLOCK)    // float4 per thread per chunk = 4
#define C4 (CHUNK / 4)         // 384 float4 per channel segment

// vout = L @ vin for all 8 channels. Grid = 256 blocks (1/CU), block = 768
// threads = 12 waves, each wave computes 4 consecutive output rows.
// vin is staged through double-buffered LDS chunks so each block reads vin
// from global exactly once (98 MB total vs 1.18 GB unstaged). L is streamed
// with coalesced float4 loads — the HBM-bound term.
__global__ __launch_bounds__(BLOCK, 3) void matpanel_kernel(
        const float* __restrict__ L,
        const float* __restrict__ vin,   // [NCH][MM]
        float* __restrict__ vout) {      // [NCH][MM]
    __shared__ float sv[2][NCH][CHUNK];  // 96 KB

    const int tid  = threadIdx.x;
    const int lane = tid & 63;
    const int wave = tid >> 6;
    const int row0 = blockIdx.x * RPB + wave * ROWS;

    float acc[ROWS][NCH];
#pragma unroll
    for (int r = 0; r < ROWS; ++r)
#pragma unroll
        for (int c = 0; c < NCH; ++c) acc[r][c] = 0.f;

    // Stage chunk 0 into buffer 0.
    {
        float4 st[F4PT];
#pragma unroll
        for (int p = 0; p < F4PT; ++p) {
            const int f  = p * BLOCK + tid;   // 0..3071
            const int ch = f / C4;
            const int c4 = f % C4;
            st[p] = *(const float4*)(vin + (size_t)ch * MM + c4 * 4);
        }
#pragma unroll
        for (int p = 0; p < F4PT; ++p) {
            const int f  = p * BLOCK + tid;
            const int ch = f / C4;
            const int c4 = f % C4;
            *(float4*)(&sv[0][ch][c4 * 4]) = st[p];
        }
    }
    __syncthreads();

    for (int ck = 0; ck < NCHUNK; ++ck) {
        const int buf   = ck & 1;
        const int jbase = ck * CHUNK;

        // Prefetch next chunk into registers (overlaps with compute below).
        float4 nx[F4PT];
        if (ck + 1 < NCHUNK) {
#pragma unroll
            for (int p = 0; p < F4PT; ++p) {
                const int f  = p * BLOCK + tid;
                const int ch = f / C4;
                const int c4 = f % C4;
                nx[p] = *(const float4*)(vin + (size_t)ch * MM +
                                         (ck + 1) * CHUNK + c4 * 4);
            }
        }

        // Compute this chunk: 6 sub-iterations of 256 columns.
#pragma unroll
        for (int s = 0; s < CHUNK / 256; ++s) {
            const int jl = s * 256 + lane * 4;
            float4 v[NCH];
#pragma unroll
            for (int c = 0; c < NCH; ++c)
                v[c] = *(const float4*)(&sv[buf][c][jl]);
#pragma unroll
            for (int r = 0; r < ROWS; ++r) {
                const float4 a =
                    *(const float4*)(L + (size_t)(row0 + r) * MM + jbase + jl);
#pragma unroll
                for (int c = 0; c < NCH; ++c) {
                    acc[r][c] += a.x * v[c].x + a.y * v[c].y
                               + a.z * v[c].z + a.w * v[c].w;
                }
            }
        }

        if (ck + 1 < NCHUNK) {
            __syncthreads();  // all waves done reading buf^1 (iteration ck-1)
#pragma unroll
            for (int p = 0; p < F4PT; ++p) {
                const int f  = p * BLOCK + tid;
                const int ch = f / C4;
                const int c4 = f % C4;
                *(float4*)(&sv[buf ^ 1][ch][c4 * 4]) = nx[p];
            }
            __syncthreads();  // writes visible before iteration ck+1 reads
        }
    }

    // Cross-lane reduction: 32 values (r*8+c) -> one per lane (lanes 0..31).
    float val[ROWS * NCH];
#pragma unroll
    for (int r = 0; r < ROWS; ++r)
#pragma unroll
        for (int c = 0; c < NCH; ++c) val[r * NCH + c] = acc[r][c];

#pragma unroll
    for (int v = 0; v < 32; ++v) val[v] += __shfl_xor(val[v], 32, 64);

#pragma unroll
    for (int d = 16; d >= 1; d >>= 1) {
        const bool up = (lane & d) != 0;
#pragma unroll
        for (int v = 0; v < 16; ++v) {
            if (v < d) {
                const float keep = up ? val[v + d] : val[v];
                const float send = up ? val[v] : val[v + d];
                const float recv = __shfl_xor(send, d, 64);
                val[v] = keep + recv;
            }
        }
    }

    if (lane < 32) {
        const int r = lane >> 3;
        const int c = lane & 7;
        vout[(size_t)c * MM + row0 + r] = val[0];
    }
}

// y[o][m] = bias[o] + sum_{c,k} theta[o][c][k] * P_k[c][m],  P_0 = x
__global__ __launch_bounds__(256) void combine_kernel(
        const float* __restrict__ x,      // [NCH][MM]  (power 0)
        const float* __restrict__ P,      // [KK-1][NCH][MM] (powers 1..4)
        const float* __restrict__ theta,  // [COUT][NCH][KK]
        const float* __restrict__ bias,   // [COUT]
        float* __restrict__ y) {          // [COUT][MM]
    const int m = blockIdx.x * blockDim.x + threadIdx.x;
    if (m >= MM) return;

    float p[KK][NCH];
#pragma unroll
    for (int c = 0; c < NCH; ++c) p[0][c] = x[(size_t)c * MM + m];
#pragma unroll
    for (int k = 1; k < KK; ++k)
#pragma unroll
        for (int c = 0; c < NCH; ++c)
            p[k][c] = P[((size_t)(k - 1) * NCH + c) * MM + m];

#pragma unroll
    for (int o = 0; o < COUT; ++o) {
        float acc = bias[o];
#pragma unroll
        for (int c = 0; c < NCH; ++c)
#pragma unroll
            for (int k = 0; k < KK; ++k)
                acc += theta[(o * NCH + c) * KK + k] * p[k][c];
        y[(size_t)o * MM + m] = acc;
    }
}

extern "C" void kernel_launch(void* const* d_in, const int* in_sizes, int n_in,
                              void* d_out, int out_size, void* d_ws, size_t ws_size,
                              hipStream_t stream) {
    const float* L     = (const float*)d_in[0];  // [MM][MM]
    const float* x     = (const float*)d_in[1];  // [1][NCH][MM]
    const float* theta = (const float*)d_in[2];  // [COUT][NCH][KK]
    const float* bias  = (const float*)d_in[3];  // [1][COUT][1]
    float* out = (float*)d_out;                  // [1][COUT][MM]
    float* P   = (float*)d_ws;                   // 4 * NCH * MM floats = 1.57 MB

    const size_t S = (size_t)NCH * MM;
    const int grid = MM / RPB;  // 256 blocks = 1 per CU

    matpanel_kernel<<<grid, BLOCK, 0, stream>>>(L, x,         P);
    matpanel_kernel<<<grid, BLOCK, 0, stream>>>(L, P,         P + S);
    matpanel_kernel<<<grid, BLOCK, 0, stream>>>(L, P + S,     P + 2 * S);
    matpanel_kernel<<<grid, BLOCK, 0, stream>>>(L, P + 2 * S, P + 3 * S);

    combine_kernel<<<(MM + 255) / 256, 256, 0, stream>>>(x, P, theta, bias, out);
}